// Round 1
// baseline (229.601 us; speedup 1.0000x reference)
//
#include <hip/hip_runtime.h>

#define B_   64
#define L_   2048
#define D_   512
#define SEG_ 16         // segments over L for the two gather passes
#define RPS_ 128        // rows per segment (L_/SEG_)
#define NS_  4          // LDS ring slots per wave (2KB each)

// counted vmem wait; "memory" clobber keeps the following ds_read from hoisting
#define WAITVM(N) asm volatile("s_waitcnt vmcnt(" #N ")" ::: "memory")

// async global->LDS DMA: per-lane global address, wave-uniform LDS base,
// HW scatters lane i to base + i*16 (16B/lane -> 1KB per instruction)
__device__ __forceinline__ void gl2lds(const float* g, float* l) {
  __builtin_amdgcn_global_load_lds(
      (const __attribute__((address_space(1))) void*)g,
      (__attribute__((address_space(3))) void*)l, 16, 0, 0);
}

// DPP add step: x += dpp_move(x, C) with bound_ctrl -> invalid lanes add 0
template <int C>
__device__ __forceinline__ float dpp_add(float x) {
  int y = __builtin_amdgcn_update_dpp(0, __builtin_bit_cast(int, x), C, 0xf, 0xf, true);
  return x + __builtin_bit_cast(float, y);
}

// full 64-lane sum, VALU-pipe only (no DS ops); result uniform via readlane 63
__device__ __forceinline__ float wave_sum_u(float x) {
  x = dpp_add<0x111>(x);   // row_shr:1
  x = dpp_add<0x112>(x);   // row_shr:2
  x = dpp_add<0x114>(x);   // row_shr:4
  x = dpp_add<0x118>(x);   // row_shr:8  -> lane 15 of each 16-row has row sum
  x = dpp_add<0x142>(x);   // row_bcast15
  x = dpp_add<0x143>(x);   // row_bcast31 -> lane 63 has full sum
  return __builtin_bit_cast(float, __builtin_amdgcn_readlane(__builtin_bit_cast(int, x), 63));
}

__device__ __forceinline__ float dot8(float4 e0, float4 e1, float4 a0, float4 a1) {
  return e0.x * a0.x + e0.y * a0.y + e0.z * a0.z + e0.w * a0.w +
         e1.x * a1.x + e1.y * a1.y + e1.z * a1.z + e1.w * a1.w;
}

// ---------- K1: partial sums of embedding rows (for h) ----------
// grid (SEG_, B_) = 1024 blocks, block 256 (4 waves). Per wave: 32 rows,
// streamed through a private 4-slot LDS ring via global_load_lds with
// counted vmcnt waits (never drain-to-0 in steady state).
__global__ __launch_bounds__(256) void k_hpart(const int* __restrict__ tok,
                                               const float* __restrict__ emb,
                                               float* __restrict__ A) {
  const int seg = blockIdx.x, b = blockIdx.y;
  const int t = threadIdx.x, w = t >> 6, lane = t & 63;
  __shared__ float stag[4 * NS_ * D_];           // 32 KB: 4 waves x 4 slots x 2KB
  float* wsl = stag + w * (NS_ * D_);
  // lanes 0..31 hold this wave's 32 tokens (lanes 32..63 duplicate)
  const int tokv = tok[b * L_ + seg * RPS_ + w * 32 + (lane & 31)];
  float acc[8];
#pragma unroll
  for (int j = 0; j < 8; ++j) acc[j] = 0.f;
  // prologue: fill the ring
#pragma unroll
  for (int i = 0; i < NS_; ++i) {
    const size_t row = (size_t)(__builtin_amdgcn_readlane(tokv, i) + 1);
    const float* rp = emb + row * D_ + lane * 4;
    gl2lds(rp, wsl + i * D_);
    gl2lds(rp + 256, wsl + i * D_ + 256);
  }
#pragma unroll
  for (int i = 0; i < 32; ++i) {
    // row i complete when outstanding <= 2*(NS_-1); tail drains 4/2/0
    if (i <= 28)      WAITVM(6);
    else if (i == 29) WAITVM(4);
    else if (i == 30) WAITVM(2);
    else              WAITVM(0);
    const float4* sp = (const float4*)(wsl + (i & (NS_ - 1)) * D_);
    const float4 e0 = sp[lane];
    const float4 e1 = sp[lane + 64];
    acc[0] += e0.x; acc[1] += e0.y; acc[2] += e0.z; acc[3] += e0.w;
    acc[4] += e1.x; acc[5] += e1.y; acc[6] += e1.z; acc[7] += e1.w;
    if (i + NS_ < 32) {  // refill the slot just consumed
      const size_t row = (size_t)(__builtin_amdgcn_readlane(tokv, i + NS_) + 1);
      const float* rp = emb + row * D_ + lane * 4;
      float* sl = wsl + (i & (NS_ - 1)) * D_;
      gl2lds(rp, sl);
      gl2lds(rp + 256, sl + 256);
    }
  }
  __syncthreads();
  float* buf = stag;                              // overlay ring as combine buffer
#pragma unroll
  for (int j = 0; j < 4; ++j) {
    buf[w * D_ + lane * 4 + j]       = acc[j];
    buf[w * D_ + 256 + lane * 4 + j] = acc[4 + j];
  }
  __syncthreads();
  const int c = 2 * t;
  const float s0 = buf[c] + buf[D_ + c] + buf[2 * D_ + c] + buf[3 * D_ + c];
  const float s1 = buf[c + 1] + buf[D_ + c + 1] + buf[2 * D_ + c + 1] + buf[3 * D_ + c + 1];
  float* o = A + ((size_t)seg * B_ + b) * D_;
  o[c] = s0; o[c + 1] = s1;
}

// ---------- K2: v[b] = W_b @ h[b] / L ----------
__global__ __launch_bounds__(256) void k_v(const float* __restrict__ A,
                                           const float* __restrict__ Wb,
                                           float* __restrict__ v) {
  const int g = blockIdx.x, b = blockIdx.y;
  const int t = threadIdx.x, w = t >> 6, lane = t & 63;
  __shared__ float sh[D_];
  float s0 = 0.f, s1 = 0.f;
#pragma unroll
  for (int s = 0; s < SEG_; ++s) {
    const float* hp = A + ((size_t)s * B_ + b) * D_;
    s0 += hp[2 * t]; s1 += hp[2 * t + 1];
  }
  sh[2 * t] = s0; sh[2 * t + 1] = s1;
  __syncthreads();
  const float4* shv = (const float4*)sh;
  const float4 a0 = shv[lane];
  const float4 a1 = shv[lane + 64];
  const int d0 = g * 64 + w * 16;
#pragma unroll 4
  for (int i = 0; i < 16; ++i) {
    const int d = d0 + i;
    const float4* rp = (const float4*)(Wb + (size_t)d * D_);
    const float r = wave_sum_u(dot8(rp[lane], rp[lane + 64], a0, a1));
    if (lane == 0) v[(size_t)b * D_ + d] = r * (1.f / (float)L_);
  }
}

// ---------- K3: fused scores+softmax+weighted-sum (flash-style) ----------
// Same LDS-ring streaming as K1; score reduce is DPP (VALU-only), so the DS
// pipe carries just the DMA writes + 2 ds_read_b128 per row.
__global__ __launch_bounds__(256) void k_flash(const int* __restrict__ tok,
                                               const float* __restrict__ emb,
                                               const float* __restrict__ v,
                                               float* __restrict__ A,
                                               float* __restrict__ ms) {
  const int seg = blockIdx.x, b = blockIdx.y;
  const int t = threadIdx.x, w = t >> 6, lane = t & 63;
  __shared__ float stag[4 * NS_ * D_];           // 32 KB ring, overlaid later
  __shared__ float red[4][2];
  float* wsl = stag + w * (NS_ * D_);
  const int tokv = tok[b * L_ + seg * RPS_ + w * 32 + (lane & 31)];
  const float4* vv = (const float4*)(v + (size_t)b * D_);
  const float4 a0 = vv[lane];
  const float4 a1 = vv[lane + 64];
  float m = -1e30f, s = 0.f;
  float acc[8];
#pragma unroll
  for (int j = 0; j < 8; ++j) acc[j] = 0.f;
#pragma unroll
  for (int i = 0; i < NS_; ++i) {
    const size_t row = (size_t)(__builtin_amdgcn_readlane(tokv, i) + 1);
    const float* rp = emb + row * D_ + lane * 4;
    gl2lds(rp, wsl + i * D_);
    gl2lds(rp + 256, wsl + i * D_ + 256);
  }
#pragma unroll
  for (int i = 0; i < 32; ++i) {
    if (i <= 28)      WAITVM(6);
    else if (i == 29) WAITVM(4);
    else if (i == 30) WAITVM(2);
    else              WAITVM(0);
    const float4* sp = (const float4*)(wsl + (i & (NS_ - 1)) * D_);
    const float4 e0 = sp[lane];
    const float4 e1 = sp[lane + 64];
    const float sc = wave_sum_u(dot8(e0, e1, a0, a1));   // uniform score
    const float mn = fmaxf(m, sc);
    const float al = __expf(m - mn);
    const float p  = __expf(sc - mn);
    s = s * al + p;
    acc[0] = acc[0] * al + p * e0.x; acc[1] = acc[1] * al + p * e0.y;
    acc[2] = acc[2] * al + p * e0.z; acc[3] = acc[3] * al + p * e0.w;
    acc[4] = acc[4] * al + p * e1.x; acc[5] = acc[5] * al + p * e1.y;
    acc[6] = acc[6] * al + p * e1.z; acc[7] = acc[7] * al + p * e1.w;
    m = mn;
    if (i + NS_ < 32) {
      const size_t row = (size_t)(__builtin_amdgcn_readlane(tokv, i + NS_) + 1);
      const float* rp = emb + row * D_ + lane * 4;
      float* sl = wsl + (i & (NS_ - 1)) * D_;
      gl2lds(rp, sl);
      gl2lds(rp + 256, sl + 256);
    }
  }
  if (lane == 0) { red[w][0] = m; red[w][1] = s; }
  __syncthreads();
  const float M = fmaxf(fmaxf(red[0][0], red[1][0]), fmaxf(red[2][0], red[3][0]));
  const float scw = __expf(m - M);     // m is wave-uniform
  float* buf = stag;                   // overlay ring as combine buffer
#pragma unroll
  for (int j = 0; j < 4; ++j) {
    buf[w * D_ + lane * 4 + j]       = acc[j] * scw;
    buf[w * D_ + 256 + lane * 4 + j] = acc[4 + j] * scw;
  }
  __syncthreads();
  const int c = 2 * t;
  const float o0 = buf[c] + buf[D_ + c] + buf[2 * D_ + c] + buf[3 * D_ + c];
  const float o1 = buf[c + 1] + buf[D_ + c + 1] + buf[2 * D_ + c + 1] + buf[3 * D_ + c + 1];
  float* oa = A + ((size_t)seg * B_ + b) * D_;   // A reuse: k_v already consumed it
  oa[c] = o0; oa[c + 1] = o1;
  if (t == 0) {
    float st = red[0][1] * __expf(red[0][0] - M) + red[1][1] * __expf(red[1][0] - M)
             + red[2][1] * __expf(red[2][0] - M) + red[3][1] * __expf(red[3][0] - M);
    ms[((size_t)seg * B_ + b) * 2]     = M;
    ms[((size_t)seg * B_ + b) * 2 + 1] = st;
  }
}

// ---------- K4: merge segment partials -> out ----------
__global__ __launch_bounds__(256) void k_merge(const float* __restrict__ A,
                                               const float* __restrict__ ms,
                                               float* __restrict__ out) {
  const int b = blockIdx.x;
  const int t = threadIdx.x;
  __shared__ float wseg[SEG_];
  if (t == 0) {
    float M = -1e30f;
#pragma unroll
    for (int s = 0; s < SEG_; ++s) M = fmaxf(M, ms[((size_t)s * B_ + b) * 2]);
    float den = 0.f;
#pragma unroll
    for (int s = 0; s < SEG_; ++s)
      den += ms[((size_t)s * B_ + b) * 2 + 1] * __expf(ms[((size_t)s * B_ + b) * 2] - M);
    const float inv = 1.f / den;
#pragma unroll
    for (int s = 0; s < SEG_; ++s)
      wseg[s] = __expf(ms[((size_t)s * B_ + b) * 2] - M) * inv;
  }
  __syncthreads();
  const int c = 2 * t;
  float o0 = 0.f, o1 = 0.f;
#pragma unroll
  for (int s = 0; s < SEG_; ++s) {
    const float* oa = A + ((size_t)s * B_ + b) * D_;
    const float ww = wseg[s];
    o0 += ww * oa[c]; o1 += ww * oa[c + 1];
  }
  out[(size_t)b * D_ + c] = o0;
  out[(size_t)b * D_ + c + 1] = o1;
}

// ---------- launch ----------
extern "C" void kernel_launch(void* const* d_in, const int* in_sizes, int n_in,
                              void* d_out, int out_size, void* d_ws, size_t ws_size,
                              hipStream_t stream) {
  const int* tok = (const int*)d_in[0];
  const float* emb = (const float*)d_in[1];
  const float* Wb  = (const float*)d_in[2];
  float* out = (float*)d_out;
  float* ws = (float*)d_ws;

  float* A  = ws;              // SEG_*B_*D_ = 524288 floats (h partials, then flash partials)
  float* v  = ws + 524288;     // B_*D_ = 32768 floats
  float* ms = ws + 557056;     // SEG_*B_*2 = 2048 floats   (total ~2.24 MB)

  k_hpart<<<dim3(SEG_, B_), 256, 0, stream>>>(tok, emb, A);
  k_v    <<<dim3(8, B_),    256, 0, stream>>>(A, Wb, v);
  k_flash<<<dim3(SEG_, B_), 256, 0, stream>>>(tok, emb, v, A, ms);
  k_merge<<<B_,             256, 0, stream>>>(A, ms, out);
}